// Round 8
// baseline (318.978 us; speedup 1.0000x reference)
//
#include <hip/hip_runtime.h>
#include <hip/hip_bf16.h>
#include <stdint.h>

typedef __bf16 bf16_t;
typedef __attribute__((ext_vector_type(8))) __bf16 bf16x8;
typedef __attribute__((ext_vector_type(4))) float f32x4;

// ---------------------------------------------------------------------------
// q8: exact re-implementation of reference to_float8.
// ---------------------------------------------------------------------------
__device__ __forceinline__ float q8(float v) {
    float a = __builtin_fabsf(v);
    float z = a + 1e-8f;
    int ei = ((__float_as_int(z) >> 23) & 0xff) - 127;
    ei = ei > 7 ? 7 : (ei < -7 ? -7 : ei);
    float p  = __int_as_float((ei + 127) << 23);
    float ip = __int_as_float((127 - ei) << 23);
    float m  = __builtin_fmaf(a, ip, -1.0f);
    float mq = __builtin_rintf(m * 8.0f) * 0.125f;
    float r  = (1.0f + mq) * p;
    return v < 0.0f ? -r : r;
}

__device__ __forceinline__ void gload_lds16(const bf16_t* g, bf16_t* l) {
    __builtin_amdgcn_global_load_lds(
        (__attribute__((address_space(1))) void*)(g),
        (__attribute__((address_space(3))) void*)(l), 16, 0, 0);
}

__device__ __forceinline__ bf16x8 cvt8(float4 a, float4 b) {
    bf16x8 o = { (bf16_t)a.x, (bf16_t)a.y, (bf16_t)a.z, (bf16_t)a.w,
                 (bf16_t)b.x, (bf16_t)b.y, (bf16_t)b.z, (bf16_t)b.w };
    return o;
}
__device__ __forceinline__ bf16x8 q8x8(float4 a, float4 b) {
    bf16x8 o = { (bf16_t)q8(a.x), (bf16_t)q8(a.y), (bf16_t)q8(a.z), (bf16_t)q8(a.w),
                 (bf16_t)q8(b.x), (bf16_t)q8(b.y), (bf16_t)q8(b.z), (bf16_t)q8(b.w) };
    return o;
}

// ---------------------------------------------------------------------------
// Homebrew device-scope grid barrier (R7 post-mortem: cooperative grid.sync()
// silently no-ops under the harness's graph capture -> race; this barrier
// depends on nothing from the runtime).
//  * Leader per block: release fence (gfx950 agent fence = L2 writeback),
//    atomicAdd arrive (device-scope, m20), spin to target, acquire fence
//    (cache invalidate -> cross-XCD L2 non-coherence handled, G16).
//  * __syncthreads() before (drains each wave's vmcnt: all block stores in
//    L2 before leader's fence) and after (releases the block).
//  * Co-residency required: 512 blocks x {64KB LDS, <=128 VGPR, 4 waves} =
//    exactly 2 blocks/CU x 256 CU. Bounded spin (2^22 polls + s_sleep) turns
//    any residency pathology into a visible wrong answer, never a hang.
// ---------------------------------------------------------------------------
__device__ __forceinline__ void grid_barrier(unsigned int* ctr, unsigned int target) {
    __syncthreads();
    if (threadIdx.x == 0) {
        __threadfence();                      // release
        atomicAdd(ctr, 1u);
        int guard = 0;
        while (__hip_atomic_load(ctr, __ATOMIC_RELAXED, __HIP_MEMORY_SCOPE_AGENT)
                   < target && guard < (1 << 22)) {
            __builtin_amdgcn_s_sleep(8);
            ++guard;
        }
        __threadfence();                      // acquire
    }
    __syncthreads();
}

// ---------------------------------------------------------------------------
// GEMM body (B^T): outf[i,j] = q8( sum_k A[i,k]*B[j,k] ), f32 out, optional
// bf16 copy. EXACT R6-verified config (57.5-58.9 us gemm1, ~905 TF,
// MfmaUtil 35%, conflicts 0, 2 blocks/CU): 128 x BN tile, BK=128, 256 thr
// (4 waves, 2Mx2N, wave 64x64), single-buffer LDS (shared 64KB arena),
// two barriers per K-tile, 16x16x32 MFMA, c^(r&15) XOR swizzle, XCD
// 8x8-patch block decode. R1-R6: schedule/vmcnt/LDS-traffic changes all
// neutral-to-negative; this structure is at its family ceiling.
// ---------------------------------------------------------------------------
template<int BN, bool DUAL>
__device__ __forceinline__ void gemm_body(const bf16_t* __restrict__ A,
                                          const bf16_t* __restrict__ B,
                                          float* __restrict__ outf,
                                          bf16_t* __restrict__ outb,
                                          int N, int K, bf16_t* smem) {
    constexpr int BM = 128;
    constexpr int BK = 128;                          // 16 chunks of 8 elems/row
    constexpr int NI = BN / 32;                      // 4 (BN=128) / 2 (BN=64)
    constexpr int A_ITS = BM * (BK / 8) / 256;       // 8
    constexpr int B_ITS = BN * (BK / 8) / 256;       // 8 / 4

    bf16_t* sA = smem;                 // 32 KB
    bf16_t* sB = smem + BM * BK;       // 32 / 16 KB

    const int tid  = threadIdx.x;
    const int lane = tid & 63;
    const int wave = tid >> 6;       // 0..3
    const int wm   = wave & 1;       // 2 m-strips of 64 rows
    const int wn   = wave >> 1;      // 2 n-strips of BN/2 cols
    const int ln16 = lane & 15;
    const int quad = lane >> 4;

    // XCD patch swizzle: 512 blocks; xcd=b&7 owns an 8x8 patch of 16x32 grid
    const int b   = blockIdx.x;
    const int xcd = b & 7;
    const int g   = b >> 3;                        // 0..63
    const int bx  = (xcd & 1) * 8 + (g & 7);       // 0..15  (N-tiles)
    const int by  = (xcd >> 1) * 8 + (g >> 3);     // 0..31  (M-tiles)
    const int brow = by * BM;
    const int bcol = bx * BN;

    // staging bases: load it has r = it*16 + (tid>>4), c = tid&15;
    // (r & 15) == tid>>4 independent of it, so one base + it*16*K covers all.
    const int srow = tid >> 4;
    const int scol = ((tid & 15) ^ srow) * 8;
    const bf16_t* gA0 = A + (size_t)(brow + srow) * K + scol;
    const bf16_t* gB0 = B + (size_t)(bcol + srow) * K + scol;

    // fragment LDS offsets (elements), s = K-substep (0..3)
    int a_off[4][4], b_off[NI][4];
#pragma unroll
    for (int im = 0; im < 4; ++im) {
        int r = wm * 64 + im * 16 + ln16;
#pragma unroll
        for (int s = 0; s < 4; ++s) {
            int cg = s * 4 + quad;
            a_off[im][s] = (r * 16 + (cg ^ (r & 15))) * 8;
        }
    }
#pragma unroll
    for (int in = 0; in < NI; ++in) {
        int r = wn * (BN / 2) + in * 16 + ln16;
#pragma unroll
        for (int s = 0; s < 4; ++s) {
            int cg = s * 4 + quad;
            b_off[in][s] = (r * 16 + (cg ^ (r & 15))) * 8;
        }
    }

    f32x4 acc[4][NI];
#pragma unroll
    for (int im = 0; im < 4; ++im)
#pragma unroll
        for (int in = 0; in < NI; ++in)
            acc[im][in] = (f32x4){0.f, 0.f, 0.f, 0.f};

    for (int kt = 0; kt < K; kt += BK) {
#pragma unroll
        for (int it = 0; it < A_ITS; ++it)
            gload_lds16(gA0 + (size_t)it * 16 * K, sA + it * 2048 + wave * 512);
        gA0 += BK;
#pragma unroll
        for (int it = 0; it < B_ITS; ++it)
            gload_lds16(gB0 + (size_t)it * 16 * K, sB + it * 2048 + wave * 512);
        gB0 += BK;
        __syncthreads();   // drains vmcnt of async LDS stores + barrier
#pragma unroll
        for (int s = 0; s < 4; ++s) {
            bf16x8 af[4], bfv[NI];
#pragma unroll
            for (int im = 0; im < 4; ++im) af[im]  = *(const bf16x8*)(sA + a_off[im][s]);
#pragma unroll
            for (int in = 0; in < NI; ++in) bfv[in] = *(const bf16x8*)(sB + b_off[in][s]);
#pragma unroll
            for (int im = 0; im < 4; ++im)
#pragma unroll
                for (int in = 0; in < NI; ++in)
                    acc[im][in] = __builtin_amdgcn_mfma_f32_16x16x32_bf16(
                        af[im], bfv[in], acc[im][in], 0, 0, 0);
        }
        __syncthreads();
    }

    // epilogue: C/D layout col = lane&15, row = quad*4 + reg
    const int rbase = quad * 4;
#pragma unroll
    for (int im = 0; im < 4; ++im) {
#pragma unroll
        for (int in = 0; in < NI; ++in) {
            int gm = brow + wm * 64 + im * 16 + rbase;
            int gn = bcol + wn * (BN / 2) + in * 16 + ln16;
#pragma unroll
            for (int r = 0; r < 4; ++r) {
                float v = q8(acc[im][in][r]);
                outf[(size_t)(gm + r) * N + gn] = v;
                if (DUAL) outb[(size_t)(gm + r) * N + gn] = (bf16_t)v;
            }
        }
    }
}

// ---------------------------------------------------------------------------
// Round-14: single fused kernel, homebrew barrier. R7 proved the fused
// structure runs and is nearly correct; only grid.sync() was broken (graph
// capture degrades cooperative launch). Phases (bit-identical math to R6 ->
// absmax must be exactly 160.0):
//   1. pack (grid-stride, 20 its/thread)   2. gemm1<128,true>   3. gemm2<64>
// ---------------------------------------------------------------------------
__global__ __launch_bounds__(256, 2)
void fused_all(const float* __restrict__ x, const float* __restrict__ u,
               const float* __restrict__ A, const float* __restrict__ B,
               const float* __restrict__ C,
               bf16_t* __restrict__ XU, bf16_t* __restrict__ AB,
               bf16_t* __restrict__ CQ, bf16_t* __restrict__ XN,
               float* __restrict__ xnf, float* __restrict__ yf,
               unsigned int* __restrict__ bar) {
    __shared__ alignas(16) bf16_t smem[32768];   // 64 KB shared arena

    // ---------------- phase 1: pack (identical math to R6 pack_all) --------
    {
        const int gid = blockIdx.x * 256 + threadIdx.x;
#pragma unroll 1
        for (int i = gid; i < 2621440; i += 131072) {
            if (i < 1048576) {                       // x -> XU[:,0:2048]
                int r = i >> 8, c = (i & 255) * 8;
                float4 v0 = *(const float4*)&x[(size_t)r * 2048 + c];
                float4 v1 = *(const float4*)&x[(size_t)r * 2048 + c + 4];
                *(bf16x8*)&XU[(size_t)r * 3072 + c] = cvt8(v0, v1);
            } else if (i < 1572864) {                // u -> XU[:,2048:3072]
                int j = i - 1048576;
                int r = j >> 7, c = (j & 127) * 8;
                float4 v0 = *(const float4*)&u[(size_t)r * 1024 + c];
                float4 v1 = *(const float4*)&u[(size_t)r * 1024 + c + 4];
                *(bf16x8*)&XU[(size_t)r * 3072 + 2048 + c] = cvt8(v0, v1);
            } else if (i < 2097152) {                // A -> AB[:,0:2048] (q8)
                int j = i - 1572864;
                int r = j >> 8, c = (j & 255) * 8;
                float4 v0 = *(const float4*)&A[(size_t)r * 2048 + c];
                float4 v1 = *(const float4*)&A[(size_t)r * 2048 + c + 4];
                *(bf16x8*)&AB[(size_t)r * 3072 + c] = q8x8(v0, v1);
            } else if (i < 2359296) {                // B -> AB[:,2048:3072]
                int j = i - 2097152;
                int r = j >> 7, c = (j & 127) * 8;
                float4 v0 = *(const float4*)&B[(size_t)r * 1024 + c];
                float4 v1 = *(const float4*)&B[(size_t)r * 1024 + c + 4];
                *(bf16x8*)&AB[(size_t)r * 3072 + 2048 + c] = q8x8(v0, v1);
            } else {                                 // C -> CQ (q8)
                int j = i - 2359296;
                int r = j >> 8, c = (j & 255) * 8;
                float4 v0 = *(const float4*)&C[(size_t)r * 2048 + c];
                float4 v1 = *(const float4*)&C[(size_t)r * 2048 + c + 4];
                *(bf16x8*)&CQ[(size_t)r * 2048 + c] = q8x8(v0, v1);
            }
        }
    }
    grid_barrier(bar + 0, 512u);

    // ---------------- phase 2: x_next = q8([x|u] @ [Aq|Bq]^T) ---------------
    gemm_body<128, true>(XU, AB, xnf, XN, 2048, 3072, smem);

    grid_barrier(bar + 16, 512u);   // separate cacheline

    // ---------------- phase 3: y = q8(x_next @ Cq^T) ------------------------
    gemm_body<64, false>(XN, CQ, yf, nullptr, 1024, 2048, smem);
}

// ---------------------------------------------------------------------------
extern "C" void kernel_launch(void* const* d_in, const int* in_sizes, int n_in,
                              void* d_out, int out_size, void* d_ws, size_t ws_size,
                              hipStream_t stream) {
    const float* x = (const float*)d_in[0];   // 4096 x 2048
    const float* u = (const float*)d_in[1];   // 4096 x 1024
    const float* A = (const float*)d_in[2];   // 2048 x 2048
    const float* B = (const float*)d_in[3];   // 2048 x 1024
    const float* C = (const float*)d_in[4];   // 1024 x 2048

    float* outf = (float*)d_out;
    float* xnf  = outf;                                 // 4096 x 2048 f32
    float* yf   = outf + (size_t)4096 * 2048;           // 4096 x 1024 f32

    uint8_t* ws = (uint8_t*)d_ws;
    bf16_t* XU = (bf16_t*)ws;                                            // 24 MB
    bf16_t* AB = (bf16_t*)(ws + (size_t)25165824);                       // 12 MB
    bf16_t* CQ = (bf16_t*)(ws + (size_t)25165824 + 12582912);            //  4 MB
    bf16_t* XN = (bf16_t*)(ws + (size_t)25165824 + 12582912 + 4194304);  // 16 MB
    // barrier counters at the workspace tail (past the 58,720,256 B in use;
    // tail placement can never write out of bounds)
    size_t bar_off = (ws_size - 128) & ~(size_t)63;
    unsigned int* bar = (unsigned int*)(ws + bar_off);

    hipMemsetAsync(bar, 0, 128, stream);
    fused_all<<<dim3(512), dim3(256), 0, stream>>>(
        x, u, A, B, C, XU, AB, CQ, XN, xnf, yf, bar);
}

// Round 9
// 209.916 us; speedup vs baseline: 1.5195x; 1.5195x over previous
//
#include <hip/hip_runtime.h>
#include <hip/hip_bf16.h>
#include <stdint.h>

typedef __bf16 bf16_t;
typedef __attribute__((ext_vector_type(8))) __bf16 bf16x8;
typedef __attribute__((ext_vector_type(4))) float f32x4;

// ---------------------------------------------------------------------------
// q8: exact re-implementation of reference to_float8.
// ---------------------------------------------------------------------------
__device__ __forceinline__ float q8(float v) {
    float a = __builtin_fabsf(v);
    float z = a + 1e-8f;
    int ei = ((__float_as_int(z) >> 23) & 0xff) - 127;
    ei = ei > 7 ? 7 : (ei < -7 ? -7 : ei);
    float p  = __int_as_float((ei + 127) << 23);
    float ip = __int_as_float((127 - ei) << 23);
    float m  = __builtin_fmaf(a, ip, -1.0f);
    float mq = __builtin_rintf(m * 8.0f) * 0.125f;
    float r  = (1.0f + mq) * p;
    return v < 0.0f ? -r : r;
}

__device__ __forceinline__ void gload_lds16(const bf16_t* g, bf16_t* l) {
    __builtin_amdgcn_global_load_lds(
        (__attribute__((address_space(1))) void*)(g),
        (__attribute__((address_space(3))) void*)(l), 16, 0, 0);
}

__device__ __forceinline__ bf16x8 cvt8(float4 a, float4 b) {
    bf16x8 o = { (bf16_t)a.x, (bf16_t)a.y, (bf16_t)a.z, (bf16_t)a.w,
                 (bf16_t)b.x, (bf16_t)b.y, (bf16_t)b.z, (bf16_t)b.w };
    return o;
}
__device__ __forceinline__ bf16x8 q8x8(float4 a, float4 b) {
    bf16x8 o = { (bf16_t)q8(a.x), (bf16_t)q8(a.y), (bf16_t)q8(a.z), (bf16_t)q8(a.w),
                 (bf16_t)q8(b.x), (bf16_t)q8(b.y), (bf16_t)q8(b.z), (bf16_t)q8(b.w) };
    return o;
}

// ---------------------------------------------------------------------------
// Fused pack kernel (R6-verbatim, verified; ~at 120MB memory roofline).
// ---------------------------------------------------------------------------
__global__ void pack_all(const float* __restrict__ x, const float* __restrict__ u,
                         const float* __restrict__ A, const float* __restrict__ B,
                         const float* __restrict__ C,
                         bf16_t* __restrict__ XU, bf16_t* __restrict__ AB,
                         bf16_t* __restrict__ CQ) {
    const unsigned bid = blockIdx.x;
    const int tid = threadIdx.x;
    if (bid < 4096u) {
        size_t r = bid; int col = tid * 8;
        float4 v0 = *(const float4*)&x[r * 2048 + col];
        float4 v1 = *(const float4*)&x[r * 2048 + col + 4];
        *(bf16x8*)&XU[r * 3072 + col] = cvt8(v0, v1);
    } else if (bid < 6144u) {
        unsigned b = bid - 4096u;
        size_t r = b * 2 + (tid >> 7); int col = (tid & 127) * 8;
        float4 v0 = *(const float4*)&u[r * 1024 + col];
        float4 v1 = *(const float4*)&u[r * 1024 + col + 4];
        *(bf16x8*)&XU[r * 3072 + 2048 + col] = cvt8(v0, v1);
    } else if (bid < 8192u) {
        size_t r = bid - 6144u; int col = tid * 8;
        float4 v0 = *(const float4*)&A[r * 2048 + col];
        float4 v1 = *(const float4*)&A[r * 2048 + col + 4];
        *(bf16x8*)&AB[r * 3072 + col] = q8x8(v0, v1);
    } else if (bid < 9216u) {
        unsigned b = bid - 8192u;
        size_t r = b * 2 + (tid >> 7); int col = (tid & 127) * 8;
        float4 v0 = *(const float4*)&B[r * 1024 + col];
        float4 v1 = *(const float4*)&B[r * 1024 + col + 4];
        *(bf16x8*)&AB[r * 3072 + 2048 + col] = q8x8(v0, v1);
    } else {
        size_t r = bid - 9216u; int col = tid * 8;
        float4 v0 = *(const float4*)&C[r * 2048 + col];
        float4 v1 = *(const float4*)&C[r * 2048 + col + 4];
        *(bf16x8*)&CQ[r * 2048 + col] = q8x8(v0, v1);
    }
}

// ---------------------------------------------------------------------------
// gemm1 Round-15: faithful m201-family port (adapted geometry).
//   out = q8([x|u] @ [Aq|Bq]^T), M=4096 N=2048 K=3072, dual f32+bf16 out.
//   BM=256 BN=128 BK=64, 512 thr = 8 waves (4M x 2N, wave 64x64 = 16 frags),
//   grid 16x16 = 256 blocks = 1 block/CU x 8 waves (same waves/CU as R6).
//   LDS ring-3 (A 3x32KB + B 3x16KB = 144KB): prefetch depth 2 tiles ~ full
//   HBM latency cover. Per tile: 2 phases x {12/4 ds_read_b128 || 1 half-tile
//   stage (3 gload_lds) -> s_barrier -> lgkmcnt(0) -> setprio(1) -> 16 MFMA
//   -> setprio(0) -> s_barrier}; ONE counted vmcnt(6) per tile at phase-1
//   tail (T4: never drain in steady state).
//   Wait ledger: end of tile t-1 has t's 6 + t+1's 6 outstanding; vmcnt(6)
//   retires t's before tile t reads ✓. Stage(t+2) targets buf[(t+2)%3], last
//   read at end of tile t-1 (barrier-ordered) ✓. Edges: prologue stages
//   t0,t1 then vmcnt(6) (retires t0); t>=NT-2 stages nothing, vmcnt(0).
//   Accumulation per element: k ascending in 32-chunks == R6 -> bit-identical
//   (absmax canary 160.0). Swizzle: R1/R3-verified c^(r&7) chunk XOR
//   (conflicts measured 0). R1-R3 failures were INVENTED schedules (counted
//   vmcnt on 2-phase = documented NULL; coarse split = documented -7-27%);
//   this is the documented fine-interleave form.
// ---------------------------------------------------------------------------
__global__ __launch_bounds__(512, 1)
void gemm1_8ph(const bf16_t* __restrict__ Ap, const bf16_t* __restrict__ Bp,
               float* __restrict__ outf, bf16_t* __restrict__ outb,
               int N, int K) {
    constexpr int BM = 256;
    constexpr int BN = 128;
    constexpr int BK = 64;

    __shared__ alignas(16) bf16_t sA[3][BM * BK];   // 3 x 32 KB
    __shared__ alignas(16) bf16_t sB[3][BN * BK];   // 3 x 16 KB

    const int tid  = threadIdx.x;
    const int lane = tid & 63;
    const int wave = tid >> 6;       // 0..7
    const int wm   = wave & 3;       // 4 m-strips of 64 rows
    const int wn   = wave >> 2;      // 2 n-strips of 64 cols
    const int ln16 = lane & 15;
    const int quad = lane >> 4;

    // XCD patch decode (R2-verified for 256-grid): xcd=b&7 owns an 8x4 patch
    const int b   = blockIdx.x;
    const int xcd = b & 7;
    const int g   = b >> 3;                          // 0..31
    const int bx  = (xcd & 1) * 8 + (g & 7);         // 0..15
    const int by  = (xcd >> 1) * 4 + (g >> 3);       // 0..15
    const int brow = by * BM;
    const int bcol = bx * BN;

    // staging pointers (verified pattern: LDS lane-linear, src chunk XOR)
    const bf16_t* gA[4];
#pragma unroll
    for (int it = 0; it < 4; ++it) {
        int L = it * 512 + tid;
        int r = L >> 3, c = L & 7;
        gA[it] = Ap + (size_t)(brow + r) * K + (c ^ (r & 7)) * 8;
    }
    const bf16_t* gB[2];
#pragma unroll
    for (int it = 0; it < 2; ++it) {
        int L = it * 512 + tid;
        int r = L >> 3, c = L & 7;
        gB[it] = Bp + (size_t)(bcol + r) * K + (c ^ (r & 7)) * 8;
    }

    // fragment LDS offsets (elements); s = K-substep (0..1)
    int a_off[4][2], b_off[2][2][2];                 // b_off[nq][in][s]
#pragma unroll
    for (int im = 0; im < 4; ++im) {
        int r = wm * 64 + im * 16 + ln16;
#pragma unroll
        for (int s = 0; s < 2; ++s) {
            int cg = s * 4 + quad;
            a_off[im][s] = (r * 8 + (cg ^ (r & 7))) * 8;
        }
    }
#pragma unroll
    for (int nq = 0; nq < 2; ++nq)
#pragma unroll
        for (int in = 0; in < 2; ++in) {
            int r = wn * 64 + nq * 32 + in * 16 + ln16;
#pragma unroll
            for (int s = 0; s < 2; ++s) {
                int cg = s * 4 + quad;
                b_off[nq][in][s] = (r * 8 + (cg ^ (r & 7))) * 8;
            }
        }

    f32x4 acc[4][4];                                 // [im][nq*2+in]
#pragma unroll
    for (int im = 0; im < 4; ++im)
#pragma unroll
        for (int jn = 0; jn < 4; ++jn)
            acc[im][jn] = (f32x4){0.f, 0.f, 0.f, 0.f};

    // one half-tile = A rows [h*128,h*128+128) (2 loads) + B rows [h*64,..) (1)
    auto STAGE_HALF = [&](int sb, int h) {
        gload_lds16(gA[2 * h],     &sA[sb][((2 * h) * 512 + wave * 64) * 8]);
        gA[2 * h] += BK;
        gload_lds16(gA[2 * h + 1], &sA[sb][((2 * h + 1) * 512 + wave * 64) * 8]);
        gA[2 * h + 1] += BK;
        gload_lds16(gB[h],         &sB[sb][(h * 512 + wave * 64) * 8]);
        gB[h] += BK;
    };

    // prologue: tiles 0,1 -> ring slots 0,1; vmcnt(6) retires tile 0
    STAGE_HALF(0, 0); STAGE_HALF(0, 1);
    STAGE_HALF(1, 0); STAGE_HALF(1, 1);
    asm volatile("s_waitcnt vmcnt(6)" ::: "memory");
    __builtin_amdgcn_s_barrier();
    asm volatile("" ::: "memory");

    const int NT = K / BK;                           // 48
    for (int t = 0; t < NT; ++t) {
        const int rb = t % 3;
        int sb = rb + 2; if (sb >= 3) sb -= 3;       // (t+2)%3
        const bool st = (t + 2 < NT);
        const bf16_t* bA = sA[rb];
        const bf16_t* bB = sB[rb];

        bf16x8 afr[4][2], bfr[2][2];

        // -------- phase 0: n-quadrant 0 --------
#pragma unroll
        for (int im = 0; im < 4; ++im) {
            afr[im][0] = *(const bf16x8*)(bA + a_off[im][0]);
            afr[im][1] = *(const bf16x8*)(bA + a_off[im][1]);
        }
#pragma unroll
        for (int in = 0; in < 2; ++in) {
            bfr[in][0] = *(const bf16x8*)(bB + b_off[0][in][0]);
            bfr[in][1] = *(const bf16x8*)(bB + b_off[0][in][1]);
        }
        if (st) STAGE_HALF(sb, 0);
        __builtin_amdgcn_s_barrier();
        asm volatile("s_waitcnt lgkmcnt(0)" ::: "memory");
        __builtin_amdgcn_s_setprio(1);
#pragma unroll
        for (int s = 0; s < 2; ++s)
#pragma unroll
            for (int im = 0; im < 4; ++im)
#pragma unroll
                for (int in = 0; in < 2; ++in)
                    acc[im][in] = __builtin_amdgcn_mfma_f32_16x16x32_bf16(
                        afr[im][s], bfr[in][s], acc[im][in], 0, 0, 0);
        __builtin_amdgcn_s_setprio(0);
        __builtin_amdgcn_s_barrier();
        asm volatile("" ::: "memory");

        // -------- phase 1: n-quadrant 1 --------
#pragma unroll
        for (int in = 0; in < 2; ++in) {
            bfr[in][0] = *(const bf16x8*)(bB + b_off[1][in][0]);
            bfr[in][1] = *(const bf16x8*)(bB + b_off[1][in][1]);
        }
        if (st) STAGE_HALF(sb, 1);
        __builtin_amdgcn_s_barrier();
        asm volatile("s_waitcnt lgkmcnt(0)" ::: "memory");
        __builtin_amdgcn_s_setprio(1);
#pragma unroll
        for (int s = 0; s < 2; ++s)
#pragma unroll
            for (int im = 0; im < 4; ++im)
#pragma unroll
                for (int in = 0; in < 2; ++in)
                    acc[im][2 + in] = __builtin_amdgcn_mfma_f32_16x16x32_bf16(
                        afr[im][s], bfr[in][s], acc[im][2 + in], 0, 0, 0);
        __builtin_amdgcn_s_setprio(0);
        if (st) asm volatile("s_waitcnt vmcnt(6)" ::: "memory");
        else    asm volatile("s_waitcnt vmcnt(0)" ::: "memory");
        __builtin_amdgcn_s_barrier();
        asm volatile("" ::: "memory");
    }

    // epilogue: C/D layout col = lane&15, row = quad*4 + reg
    const int rbase = quad * 4;
#pragma unroll
    for (int im = 0; im < 4; ++im) {
#pragma unroll
        for (int nq = 0; nq < 2; ++nq)
#pragma unroll
            for (int in = 0; in < 2; ++in) {
                int gm = brow + wm * 64 + im * 16 + rbase;
                int gn = bcol + wn * 64 + nq * 32 + in * 16 + ln16;
#pragma unroll
                for (int r = 0; r < 4; ++r) {
                    float v = q8(acc[im][nq * 2 + in][r]);
                    outf[(size_t)(gm + r) * N + gn] = v;
                    outb[(size_t)(gm + r) * N + gn] = (bf16_t)v;
                }
            }
    }
}

// ---------------------------------------------------------------------------
// gemm2 (R6-verbatim, verified ~22-25us): 128x64 tile, BK=128, 256 thr,
// 4 waves 2x2 (wave 64x32), single-buffer 48KB LDS, grid 512, XCD 8x8 patch.
// ---------------------------------------------------------------------------
__global__ __launch_bounds__(256, 3)
void gemm_q8_v6(const bf16_t* __restrict__ A, const bf16_t* __restrict__ B,
                float* __restrict__ outf, int N, int K) {
    constexpr int BM = 128;
    constexpr int BK = 128;
    constexpr int BN = 64;
    constexpr int NI = BN / 32;                      // 2
    constexpr int A_ITS = BM * (BK / 8) / 256;       // 8
    constexpr int B_ITS = BN * (BK / 8) / 256;       // 4

    __shared__ alignas(16) bf16_t sA[BM * BK];
    __shared__ alignas(16) bf16_t sB[BN * BK];

    const int tid  = threadIdx.x;
    const int lane = tid & 63;
    const int wave = tid >> 6;
    const int wm   = wave & 1;
    const int wn   = wave >> 1;
    const int ln16 = lane & 15;
    const int quad = lane >> 4;

    const int b   = blockIdx.x;
    const int xcd = b & 7;
    const int g   = b >> 3;
    const int bx  = (xcd & 1) * 8 + (g & 7);
    const int by  = (xcd >> 1) * 8 + (g >> 3);
    const int brow = by * BM;
    const int bcol = bx * BN;

    const int srow = tid >> 4;
    const int scol = ((tid & 15) ^ srow) * 8;
    const bf16_t* gA0 = A + (size_t)(brow + srow) * K + scol;
    const bf16_t* gB0 = B + (size_t)(bcol + srow) * K + scol;

    int a_off[4][4], b_off[NI][4];
#pragma unroll
    for (int im = 0; im < 4; ++im) {
        int r = wm * 64 + im * 16 + ln16;
#pragma unroll
        for (int s = 0; s < 4; ++s) {
            int cg = s * 4 + quad;
            a_off[im][s] = (r * 16 + (cg ^ (r & 15))) * 8;
        }
    }
#pragma unroll
    for (int in = 0; in < NI; ++in) {
        int r = wn * (BN / 2) + in * 16 + ln16;
#pragma unroll
        for (int s = 0; s < 4; ++s) {
            int cg = s * 4 + quad;
            b_off[in][s] = (r * 16 + (cg ^ (r & 15))) * 8;
        }
    }

    f32x4 acc[4][NI];
#pragma unroll
    for (int im = 0; im < 4; ++im)
#pragma unroll
        for (int in = 0; in < NI; ++in)
            acc[im][in] = (f32x4){0.f, 0.f, 0.f, 0.f};

    for (int kt = 0; kt < K; kt += BK) {
#pragma unroll
        for (int it = 0; it < A_ITS; ++it)
            gload_lds16(gA0 + (size_t)it * 16 * K, sA + it * 2048 + wave * 512);
        gA0 += BK;
#pragma unroll
        for (int it = 0; it < B_ITS; ++it)
            gload_lds16(gB0 + (size_t)it * 16 * K, sB + it * 2048 + wave * 512);
        gB0 += BK;
        __syncthreads();
#pragma unroll
        for (int s = 0; s < 4; ++s) {
            bf16x8 af[4], bfv[NI];
#pragma unroll
            for (int im = 0; im < 4; ++im) af[im]  = *(const bf16x8*)(sA + a_off[im][s]);
#pragma unroll
            for (int in = 0; in < NI; ++in) bfv[in] = *(const bf16x8*)(sB + b_off[in][s]);
#pragma unroll
            for (int im = 0; im < 4; ++im)
#pragma unroll
                for (int in = 0; in < NI; ++in)
                    acc[im][in] = __builtin_amdgcn_mfma_f32_16x16x32_bf16(
                        af[im], bfv[in], acc[im][in], 0, 0, 0);
        }
        __syncthreads();
    }

    const int rbase = quad * 4;
#pragma unroll
    for (int im = 0; im < 4; ++im) {
#pragma unroll
        for (int in = 0; in < NI; ++in) {
            int gm = brow + wm * 64 + im * 16 + rbase;
            int gn = bcol + wn * (BN / 2) + in * 16 + ln16;
#pragma unroll
            for (int r = 0; r < 4; ++r)
                outf[(size_t)(gm + r) * N + gn] = q8(acc[im][in][r]);
        }
    }
}

// ---------------------------------------------------------------------------
extern "C" void kernel_launch(void* const* d_in, const int* in_sizes, int n_in,
                              void* d_out, int out_size, void* d_ws, size_t ws_size,
                              hipStream_t stream) {
    const float* x = (const float*)d_in[0];   // 4096 x 2048
    const float* u = (const float*)d_in[1];   // 4096 x 1024
    const float* A = (const float*)d_in[2];   // 2048 x 2048
    const float* B = (const float*)d_in[3];   // 2048 x 1024
    const float* C = (const float*)d_in[4];   // 1024 x 2048

    float* outf = (float*)d_out;
    float* xnf  = outf;                                 // 4096 x 2048 f32
    float* yf   = outf + (size_t)4096 * 2048;           // 4096 x 1024 f32

    uint8_t* ws = (uint8_t*)d_ws;
    bf16_t* XU = (bf16_t*)ws;                                            // 24 MB
    bf16_t* AB = (bf16_t*)(ws + (size_t)25165824);                       // 12 MB
    bf16_t* CQ = (bf16_t*)(ws + (size_t)25165824 + 12582912);            //  4 MB
    bf16_t* XN = (bf16_t*)(ws + (size_t)25165824 + 12582912 + 4194304);  // 16 MB

    pack_all<<<dim3(10240), 256, 0, stream>>>(x, u, A, B, C, XU, AB, CQ);

    // x_next = q8([x|u] @ [Aq|Bq]^T): M=4096 N=2048 K=3072; grid 16x16
    gemm1_8ph<<<dim3(256), 512, 0, stream>>>(XU, AB, xnf, XN, 2048, 3072);
    // y = q8(x_next @ Cq^T): M=4096 N=1024 K=2048; grid 16x32 = 512
    gemm_q8_v6<<<dim3(512), 256, 0, stream>>>(XN, CQ, yf, 1024, 2048);
}

// Round 10
// 201.206 us; speedup vs baseline: 1.5853x; 1.0433x over previous
//
#include <hip/hip_runtime.h>
#include <hip/hip_bf16.h>
#include <stdint.h>

typedef __bf16 bf16_t;
typedef __attribute__((ext_vector_type(8))) __bf16 bf16x8;
typedef __attribute__((ext_vector_type(4))) float f32x4;

// ---------------------------------------------------------------------------
// q8: exact re-implementation of reference to_float8.
// ---------------------------------------------------------------------------
__device__ __forceinline__ float q8(float v) {
    float a = __builtin_fabsf(v);
    float z = a + 1e-8f;
    int ei = ((__float_as_int(z) >> 23) & 0xff) - 127;
    ei = ei > 7 ? 7 : (ei < -7 ? -7 : ei);
    float p  = __int_as_float((ei + 127) << 23);
    float ip = __int_as_float((127 - ei) << 23);
    float m  = __builtin_fmaf(a, ip, -1.0f);
    float mq = __builtin_rintf(m * 8.0f) * 0.125f;
    float r  = (1.0f + mq) * p;
    return v < 0.0f ? -r : r;
}

__device__ __forceinline__ void gload_lds16(const bf16_t* g, bf16_t* l) {
    __builtin_amdgcn_global_load_lds(
        (__attribute__((address_space(1))) void*)(g),
        (__attribute__((address_space(3))) void*)(l), 16, 0, 0);
}

__device__ __forceinline__ bf16x8 cvt8(float4 a, float4 b) {
    bf16x8 o = { (bf16_t)a.x, (bf16_t)a.y, (bf16_t)a.z, (bf16_t)a.w,
                 (bf16_t)b.x, (bf16_t)b.y, (bf16_t)b.z, (bf16_t)b.w };
    return o;
}
__device__ __forceinline__ bf16x8 q8x8(float4 a, float4 b) {
    bf16x8 o = { (bf16_t)q8(a.x), (bf16_t)q8(a.y), (bf16_t)q8(a.z), (bf16_t)q8(a.w),
                 (bf16_t)q8(b.x), (bf16_t)q8(b.y), (bf16_t)q8(b.z), (bf16_t)q8(b.w) };
    return o;
}

// ---------------------------------------------------------------------------
// Fused pack kernel, 10240 blocks x 256 threads, 8 elems/thread, 16B stores.
// At its ~118 MB memory roofline (~18 us at 6.3 TB/s achievable).
// ---------------------------------------------------------------------------
__global__ void pack_all(const float* __restrict__ x, const float* __restrict__ u,
                         const float* __restrict__ A, const float* __restrict__ B,
                         const float* __restrict__ C,
                         bf16_t* __restrict__ XU, bf16_t* __restrict__ AB,
                         bf16_t* __restrict__ CQ) {
    const unsigned bid = blockIdx.x;
    const int tid = threadIdx.x;
    if (bid < 4096u) {
        size_t r = bid; int col = tid * 8;
        float4 v0 = *(const float4*)&x[r * 2048 + col];
        float4 v1 = *(const float4*)&x[r * 2048 + col + 4];
        *(bf16x8*)&XU[r * 3072 + col] = cvt8(v0, v1);
    } else if (bid < 6144u) {
        unsigned b = bid - 4096u;
        size_t r = b * 2 + (tid >> 7); int col = (tid & 127) * 8;
        float4 v0 = *(const float4*)&u[r * 1024 + col];
        float4 v1 = *(const float4*)&u[r * 1024 + col + 4];
        *(bf16x8*)&XU[r * 3072 + 2048 + col] = cvt8(v0, v1);
    } else if (bid < 8192u) {
        size_t r = bid - 6144u; int col = tid * 8;
        float4 v0 = *(const float4*)&A[r * 2048 + col];
        float4 v1 = *(const float4*)&A[r * 2048 + col + 4];
        *(bf16x8*)&AB[r * 3072 + col] = q8x8(v0, v1);
    } else if (bid < 9216u) {
        unsigned b = bid - 8192u;
        size_t r = b * 2 + (tid >> 7); int col = (tid & 127) * 8;
        float4 v0 = *(const float4*)&B[r * 1024 + col];
        float4 v1 = *(const float4*)&B[r * 1024 + col + 4];
        *(bf16x8*)&AB[r * 3072 + 2048 + col] = q8x8(v0, v1);
    } else {
        size_t r = bid - 9216u; int col = tid * 8;
        float4 v0 = *(const float4*)&C[r * 2048 + col];
        float4 v1 = *(const float4*)&C[r * 2048 + col + 4];
        *(bf16x8*)&CQ[r * 2048 + col] = q8x8(v0, v1);
    }
}

// ---------------------------------------------------------------------------
// GEMM (B^T): outf[i,j] = q8( sum_k A[i,k]*B[j,k] ), f32 out, optional bf16.
// SESSION-BEST verified config (R6: 198.4 us total; gemm1 57.5-58.9 us,
// ~905 TF, MfmaUtil 35%, conflicts 0, 2 blocks/CU):
//  * 128 x BN tile, BK=128, 256 thr (4 waves, 2Mx2N, wave 64x64),
//    single-buffer 64/48KB LDS, two barriers per K-tile, 16x16x32 MFMA,
//    c^(r&15) XOR swizzle, XCD 8x8-patch block decode, grid 512.
//  * SESSION LEDGER (do not re-litigate): hand-scheduled pipelines all
//    regressed vs this structure -- R1 counted-vmcnt dbuf +10%, R2 4-phase
//    ring +29%, R3 3-ring 1-barrier +42%, R9 faithful m201-geometry port
//    +24%. Cause each time: losing the co-resident 2nd block (m114 overlap)
//    and/or shrinking MFMA-per-barrier. Wave 64x64 (R6) vs 32x64 (R0) was
//    neutral-to-slightly-positive; LDS-BW theory falsified in R6.
//  * R8 proved the ~100us bench-vs-kernel gap is FIXED harness overhead
//    (1 fused dispatch of 219us still benched 319us); fusion also degraded
//    phase compute 1.7x. Kernel side is at its validated optimum.
// ---------------------------------------------------------------------------
template<int BN, bool DUAL>
__global__ __launch_bounds__(256, (BN == 128) ? 2 : 3)
void gemm_q8_v6(const bf16_t* __restrict__ A, const bf16_t* __restrict__ B,
                float* __restrict__ outf, bf16_t* __restrict__ outb,
                int N, int K) {
    constexpr int BM = 128;
    constexpr int BK = 128;                          // 16 chunks of 8 elems/row
    constexpr int NI = BN / 32;                      // 4 (BN=128) / 2 (BN=64)
    constexpr int A_ITS = BM * (BK / 8) / 256;       // 8
    constexpr int B_ITS = BN * (BK / 8) / 256;       // 8 / 4

    __shared__ alignas(16) bf16_t sA[BM * BK];
    __shared__ alignas(16) bf16_t sB[BN * BK];

    const int tid  = threadIdx.x;
    const int lane = tid & 63;
    const int wave = tid >> 6;       // 0..3
    const int wm   = wave & 1;       // 2 m-strips of 64 rows
    const int wn   = wave >> 1;      // 2 n-strips of BN/2 cols
    const int ln16 = lane & 15;
    const int quad = lane >> 4;

    // XCD patch swizzle: 512 blocks; xcd=b&7 owns an 8x8 patch of 16x32 grid
    const int b   = blockIdx.x;
    const int xcd = b & 7;
    const int g   = b >> 3;                        // 0..63
    const int bx  = (xcd & 1) * 8 + (g & 7);       // 0..15  (N-tiles)
    const int by  = (xcd >> 1) * 8 + (g >> 3);     // 0..31  (M-tiles)
    const int brow = by * BM;
    const int bcol = bx * BN;

    // staging bases: load it has r = it*16 + (tid>>4), c = tid&15;
    // (r & 15) == tid>>4 independent of it, so one base + it*16*K covers all.
    const int srow = tid >> 4;
    const int scol = ((tid & 15) ^ srow) * 8;
    const bf16_t* gA0 = A + (size_t)(brow + srow) * K + scol;
    const bf16_t* gB0 = B + (size_t)(bcol + srow) * K + scol;

    // fragment LDS offsets (elements), s = K-substep (0..3)
    int a_off[4][4], b_off[NI][4];
#pragma unroll
    for (int im = 0; im < 4; ++im) {
        int r = wm * 64 + im * 16 + ln16;
#pragma unroll
        for (int s = 0; s < 4; ++s) {
            int cg = s * 4 + quad;
            a_off[im][s] = (r * 16 + (cg ^ (r & 15))) * 8;
        }
    }
#pragma unroll
    for (int in = 0; in < NI; ++in) {
        int r = wn * (BN / 2) + in * 16 + ln16;
#pragma unroll
        for (int s = 0; s < 4; ++s) {
            int cg = s * 4 + quad;
            b_off[in][s] = (r * 16 + (cg ^ (r & 15))) * 8;
        }
    }

    f32x4 acc[4][NI];
#pragma unroll
    for (int im = 0; im < 4; ++im)
#pragma unroll
        for (int in = 0; in < NI; ++in)
            acc[im][in] = (f32x4){0.f, 0.f, 0.f, 0.f};

    for (int kt = 0; kt < K; kt += BK) {
#pragma unroll
        for (int it = 0; it < A_ITS; ++it)
            gload_lds16(gA0 + (size_t)it * 16 * K, sA + it * 2048 + wave * 512);
        gA0 += BK;
#pragma unroll
        for (int it = 0; it < B_ITS; ++it)
            gload_lds16(gB0 + (size_t)it * 16 * K, sB + it * 2048 + wave * 512);
        gB0 += BK;
        __syncthreads();   // drains vmcnt of async LDS stores + barrier
#pragma unroll
        for (int s = 0; s < 4; ++s) {
            bf16x8 af[4], bfv[NI];
#pragma unroll
            for (int im = 0; im < 4; ++im) af[im]  = *(const bf16x8*)(sA + a_off[im][s]);
#pragma unroll
            for (int in = 0; in < NI; ++in) bfv[in] = *(const bf16x8*)(sB + b_off[in][s]);
#pragma unroll
            for (int im = 0; im < 4; ++im)
#pragma unroll
                for (int in = 0; in < NI; ++in)
                    acc[im][in] = __builtin_amdgcn_mfma_f32_16x16x32_bf16(
                        af[im], bfv[in], acc[im][in], 0, 0, 0);
        }
        __syncthreads();
    }

    // epilogue: C/D layout col = lane&15, row = quad*4 + reg
    const int rbase = quad * 4;
#pragma unroll
    for (int im = 0; im < 4; ++im) {
#pragma unroll
        for (int in = 0; in < NI; ++in) {
            int gm = brow + wm * 64 + im * 16 + rbase;
            int gn = bcol + wn * (BN / 2) + in * 16 + ln16;
#pragma unroll
            for (int r = 0; r < 4; ++r) {
                float v = q8(acc[im][in][r]);
                outf[(size_t)(gm + r) * N + gn] = v;
                if (DUAL) outb[(size_t)(gm + r) * N + gn] = (bf16_t)v;
            }
        }
    }
}

// ---------------------------------------------------------------------------
extern "C" void kernel_launch(void* const* d_in, const int* in_sizes, int n_in,
                              void* d_out, int out_size, void* d_ws, size_t ws_size,
                              hipStream_t stream) {
    const float* x = (const float*)d_in[0];   // 4096 x 2048
    const float* u = (const float*)d_in[1];   // 4096 x 1024
    const float* A = (const float*)d_in[2];   // 2048 x 2048
    const float* B = (const float*)d_in[3];   // 2048 x 1024
    const float* C = (const float*)d_in[4];   // 1024 x 2048

    float* outf = (float*)d_out;
    float* xnf  = outf;                                 // 4096 x 2048 f32
    float* yf   = outf + (size_t)4096 * 2048;           // 4096 x 1024 f32

    uint8_t* ws = (uint8_t*)d_ws;
    bf16_t* XU = (bf16_t*)ws;                                            // 24 MB
    bf16_t* AB = (bf16_t*)(ws + (size_t)25165824);                       // 12 MB
    bf16_t* CQ = (bf16_t*)(ws + (size_t)25165824 + 12582912);            //  4 MB
    bf16_t* XN = (bf16_t*)(ws + (size_t)25165824 + 12582912 + 4194304);  // 16 MB

    pack_all<<<dim3(10240), 256, 0, stream>>>(x, u, A, B, C, XU, AB, CQ);

    // x_next = q8([x|u] @ [Aq|Bq]^T): M=4096 N=2048 K=3072; grid 32x16=512
    gemm_q8_v6<128, true><<<dim3(512), 256, 0, stream>>>(
        XU, AB, xnf, XN, 2048, 3072);
    // y = q8(x_next @ Cq^T): M=4096 N=1024 K=2048; grid 32x16=512
    gemm_q8_v6<64, false><<<dim3(512), 256, 0, stream>>>(
        XN, CQ, yf, nullptr, 1024, 2048);
}